// Round 1
// baseline (2285.739 us; speedup 1.0000x reference)
//
#include <hip/hip_runtime.h>

// Problem constants (from reference): N=512, BS=64, DIM=256, SIZE=8192
#define T_TOTAL 32768   // N*BS queries
#define D       256     // dim
#define K       8192    // vocab size
#define QT      64      // queries per block
#define CT      128     // codes per tile
#define DT      64      // d-chunk staged in LDS
#define LP      68      // padded LDS row length in floats (+4 keeps 16B align, spreads bank-quads)

// ---------------- kernel 1: half squared norms of vocab rows ----------------
__global__ void hv2_kernel(const float* __restrict__ vocab, float* __restrict__ hv2) {
    // one wave (64 lanes) per code row; block = 4 waves
    int code = blockIdx.x * 4 + (threadIdx.x >> 6);
    int lane = threadIdx.x & 63;
    const float4* row = (const float4*)(vocab + (size_t)code * D);
    float4 v = row[lane];                       // 64 lanes * 4 = 256 elements
    float s = v.x * v.x + v.y * v.y + v.z * v.z + v.w * v.w;
    #pragma unroll
    for (int off = 32; off; off >>= 1) s += __shfl_down(s, off, 64);
    if (lane == 0) hv2[code] = 0.5f * s;
}

// ---------------- kernel 2: argmin_k (0.5*|v_k|^2 - x.v_k) ----------------
__launch_bounds__(256, 2)
__global__ void argmin_kernel(const float* __restrict__ seq,
                              const float* __restrict__ vocab,
                              const float* __restrict__ hv2,
                              int* __restrict__ out_idx) {
    __shared__ float Qs[QT][LP];   // [query][d]  17.4 KB
    __shared__ float Vs[CT][LP];   // [code][d]   34.8 KB  -> 52 KB total, 2 blocks/CU

    const int t  = threadIdx.x;
    const int tx = t & 15;         // code-group lane: c = tx + 16j
    const int ty = t >> 4;         // query-group lane: q = ty + 16i
    const int q0 = blockIdx.x * QT;

    const float4* seq4 = (const float4*)seq;
    const float4* voc4 = (const float4*)vocab;

    float best[4];
    int   bidx[4];
    #pragma unroll
    for (int i = 0; i < 4; ++i) { best[i] = 3.4e38f; bidx[i] = 0; }

    for (int c0 = 0; c0 < K; c0 += CT) {
        float acc[4][8];
        #pragma unroll
        for (int i = 0; i < 4; ++i)
            #pragma unroll
            for (int j = 0; j < 8; ++j) acc[i][j] = 0.0f;

        for (int dt = 0; dt < D; dt += DT) {
            __syncthreads();   // previous tile's compute done before overwrite
            // stage Q chunk: 64 rows x 16 float4 (1024 float4s, 4/thread), coalesced
            #pragma unroll
            for (int i = 0; i < 4; ++i) {
                int f  = t + 256 * i;
                int q  = f >> 4;
                int dq = f & 15;
                float4 v = seq4[(size_t)(q0 + q) * (D / 4) + (dt / 4) + dq];
                *(float4*)&Qs[q][dq * 4] = v;
            }
            // stage V chunk: 128 rows x 16 float4 (2048 float4s, 8/thread), coalesced
            #pragma unroll
            for (int i = 0; i < 8; ++i) {
                int f  = t + 256 * i;
                int c  = f >> 4;
                int dq = f & 15;
                float4 v = voc4[(size_t)(c0 + c) * (D / 4) + (dt / 4) + dq];
                *(float4*)&Vs[c][dq * 4] = v;
            }
            __syncthreads();

            // compute: 16 d4-chunks; per chunk 12 ds_read_b128 + 128 v_fma (VALU-bound)
            #pragma unroll 4
            for (int dc = 0; dc < DT; dc += 4) {
                float4 qf[4], vf[8];
                #pragma unroll
                for (int i = 0; i < 4; ++i) qf[i] = *(const float4*)&Qs[ty + 16 * i][dc];
                #pragma unroll
                for (int j = 0; j < 8; ++j) vf[j] = *(const float4*)&Vs[tx + 16 * j][dc];
                #pragma unroll
                for (int i = 0; i < 4; ++i)
                    #pragma unroll
                    for (int j = 0; j < 8; ++j) {
                        float a = acc[i][j];
                        a = fmaf(qf[i].x, vf[j].x, a);
                        a = fmaf(qf[i].y, vf[j].y, a);
                        a = fmaf(qf[i].z, vf[j].z, a);
                        a = fmaf(qf[i].w, vf[j].w, a);
                        acc[i][j] = a;
                    }
            }
        }

        // epilogue: s = 0.5*|v|^2 - dot ; running argmin (ascending c order per thread)
        #pragma unroll
        for (int j = 0; j < 8; ++j) {
            int c = c0 + tx + 16 * j;
            float hv = hv2[c];
            #pragma unroll
            for (int i = 0; i < 4; ++i) {
                float s = hv - acc[i][j];
                if (s < best[i]) { best[i] = s; bidx[i] = c; }
            }
        }
    }

    // reduce across the 16 tx lanes sharing each query (lanes are contiguous in-wave)
    #pragma unroll
    for (int off = 1; off < 16; off <<= 1) {
        #pragma unroll
        for (int i = 0; i < 4; ++i) {
            float ob = __shfl_xor(best[i], off, 64);
            int   oi = __shfl_xor(bidx[i], off, 64);
            if (ob < best[i] || (ob == best[i] && oi < bidx[i])) {
                best[i] = ob; bidx[i] = oi;
            }
        }
    }
    if (tx == 0) {
        #pragma unroll
        for (int i = 0; i < 4; ++i) out_idx[q0 + ty + 16 * i] = bidx[i];
    }
}

// ---------------- kernel 3: gather vocab rows + emit indices as f32 ----------------
__global__ void gather_kernel(const float* __restrict__ vocab,
                              const int* __restrict__ idx,
                              float* __restrict__ out) {
    int r    = blockIdx.x * 4 + (threadIdx.x >> 6);  // one wave per output row
    int lane = threadIdx.x & 63;
    int k = idx[r];
    const float4* src = (const float4*)(vocab + (size_t)k * D);
    float4*       dst = (float4*)(out + (size_t)r * D);
    dst[lane] = src[lane];
    if (lane == 0) out[(size_t)T_TOTAL * D + r] = (float)k;  // indices region, as f32
}

extern "C" void kernel_launch(void* const* d_in, const int* in_sizes, int n_in,
                              void* d_out, int out_size, void* d_ws, size_t ws_size,
                              hipStream_t stream) {
    const float* seq   = (const float*)d_in[0];   // [T_TOTAL, D] f32
    const float* vocab = (const float*)d_in[1];   // [K, D] f32
    float* out = (float*)d_out;                   // [T*D quantized | T indices-as-f32]

    float* hv2 = (float*)d_ws;                               // K floats
    int*   idx = (int*)((char*)d_ws + K * sizeof(float));    // T ints

    hipLaunchKernelGGL(hv2_kernel,    dim3(K / 4),        dim3(256), 0, stream, vocab, hv2);
    hipLaunchKernelGGL(argmin_kernel, dim3(T_TOTAL / QT), dim3(256), 0, stream, seq, vocab, hv2, idx);
    hipLaunchKernelGGL(gather_kernel, dim3(T_TOTAL / 4),  dim3(256), 0, stream, vocab, idx, out);
}